// Round 8
// baseline (93.781 us; speedup 1.0000x reference)
//
#include <hip/hip_runtime.h>

#define MAX_SEQ   2048
#define LAT_SEQ   1024
#define DIM       1024
#define DLAT      5
#define K_CB      4375
#define ZERO_IDX  2187   // (0+3)*625 + (0+2)*125 + (0+2)*25 + (0+2)*5 + (0+2)

// ws ints: used[0..4374], uniq = [4375], ticket = [4376]  (memset to 0 each call)

// ---------------------------------------------------------------------------
// Fused encode -> quantize -> decode. 256-thread blocks (4 waves), 2
// (unmasked, masked) token pairs per wave -> grid 2048. Weights staged in LDS.
// Codebook usage counted incrementally with first-touch atomics (no fences);
// the last block (arrival ticket) writes the 3 scalar outputs.
__global__ __launch_bounds__(256) void fsq_main(
    const float* __restrict__ x,
    const float* __restrict__ Wenc,   // [1024][5]
    const float* __restrict__ Wdec,   // [5][1024]
    float* __restrict__ xout,         // [32768][1024]
    float* __restrict__ ze,           // [32768][5]
    float* __restrict__ zq,           // [32768][5]
    int*   __restrict__ used,         // [4375] + uniq + ticket
    float* __restrict__ scal)         // 3 scalars
{
    __shared__ float wencT[DLAT * DIM];   // [5][1024]
    __shared__ float wdecS[DLAT * DIM];   // [5][1024]

    const int tid  = threadIdx.x;
    const int wave = tid >> 6;
    const int lane = tid & 63;
    const int u0   = (blockIdx.x * 4 + wave) * 2;    // unmasked ordinal base

    int* const uniq_ctr   = used + K_CB;
    int* const ticket_ctr = used + K_CB + 1;

    // block 0 marks the always-used all-zero code (masked tokens decode to it)
    if (blockIdx.x == 0 && tid == 0) {
        if (atomicExch(used + ZERO_IDX, 1) == 0) atomicAdd(uniq_ctr, 1);
    }

    int t[2];  long long row[2], rowm[2];
    #pragma unroll
    for (int p = 0; p < 2; ++p) {
        const int u = u0 + p;
        const int b = u >> 10, s = u & 1023;
        t[p]    = b * MAX_SEQ + s;                    // unmasked token
        row[p]  = (long long)t[p] * DIM;
        rowm[p] = row[p] + (long long)LAT_SEQ * DIM;  // masked partner row
    }

    // ---- issue x loads early (8 float4 in flight)
    float4 v[2][4];
    #pragma unroll
    for (int p = 0; p < 2; ++p)
        #pragma unroll
        for (int q = 0; q < 4; ++q)
            v[p][q] = *(const float4*)(x + row[p] + q * 256 + lane * 4);

    // ---- masked partners: independent zero-store work
    const float4 z4 = make_float4(0.f, 0.f, 0.f, 0.f);
    #pragma unroll
    for (int p = 0; p < 2; ++p) {
        #pragma unroll
        for (int q = 0; q < 4; ++q)
            *(float4*)(xout + rowm[p] + q * 256 + lane * 4) = z4;
        if (lane < DLAT) {
            const int tm = t[p] + LAT_SEQ;
            ze[tm * DLAT + lane] = 0.f;
            zq[tm * DLAT + lane] = 0.f;
        }
    }

    // ---- cooperative weight staging into LDS
    {
        const float4* src = (const float4*)Wdec;      // [5][1024] already coalesced
        float4*       dst = (float4*)wdecS;
        #pragma unroll
        for (int m = 0; m < 5; ++m)
            dst[tid + 256 * m] = src[tid + 256 * m];
        #pragma unroll
        for (int m = 0; m < 20; ++m) {                // WencT[e][d] = Wenc[d][e]
            const int k = tid + 256 * m;
            const int e = k >> 10, d = k & 1023;
            wencT[k] = Wenc[d * DLAT + e];
        }
    }
    __syncthreads();

    // ---- encode: h[p][e] = sum_d x[t_p,d] * Wenc[d,e]
    float acc[2][DLAT] = {};
    #pragma unroll
    for (int q = 0; q < 4; ++q) {
        const int c0 = q * 256 + lane * 4;
        #pragma unroll
        for (int e = 0; e < DLAT; ++e) {
            const float4 w = *(const float4*)(wencT + e * DIM + c0);
            #pragma unroll
            for (int p = 0; p < 2; ++p)
                acc[p][e] += v[p][q].x * w.x + v[p][q].y * w.y
                           + v[p][q].z * w.z + v[p][q].w * w.w;
        }
    }
    #pragma unroll
    for (int p = 0; p < 2; ++p)
        #pragma unroll
        for (int e = 0; e < DLAT; ++e) {
            float a = acc[p][e];
            #pragma unroll
            for (int o = 32; o > 0; o >>= 1) a += __shfl_xor(a, o, 64);
            acc[p][e] = a;
        }

    // ---- quantize: z_q = rint(half * tanh(h))  (rint = half-to-even)
    const float halfv[DLAT] = {3.f, 2.f, 2.f, 2.f, 2.f};
    float zqv[2][DLAT];
    #pragma unroll
    for (int p = 0; p < 2; ++p) {
        int ci[DLAT];
        #pragma unroll
        for (int e = 0; e < DLAT; ++e) {
            const float zsq = halfv[e] * tanhf(acc[p][e]);
            zqv[p][e] = rintf(zsq);
            ci[e]     = (int)zqv[p][e];
        }
        if (lane < DLAT) {
            ze[t[p] * DLAT + lane] = acc[p][lane];
            zq[t[p] * DLAT + lane] = zqv[p][lane];
        }
        if (lane == 0) {
            const int idx = ((((ci[0] + 3) * 5 + (ci[1] + 2)) * 5 + (ci[2] + 2)) * 5
                              + (ci[3] + 2)) * 5 + (ci[4] + 2);
            if (atomicExch(used + idx, 1) == 0) atomicAdd(uniq_ctr, 1);
        }
    }

    // ---- decode: x_out[t,d] = sum_e z_q[e] * Wdec[e,d]
    #pragma unroll
    for (int q = 0; q < 4; ++q) {
        const int c0 = q * 256 + lane * 4;
        float4 o[2] = {make_float4(0.f,0.f,0.f,0.f), make_float4(0.f,0.f,0.f,0.f)};
        #pragma unroll
        for (int e = 0; e < DLAT; ++e) {
            const float4 w = *(const float4*)(wdecS + e * DIM + c0);
            #pragma unroll
            for (int p = 0; p < 2; ++p) {
                o[p].x += zqv[p][e] * w.x; o[p].y += zqv[p][e] * w.y;
                o[p].z += zqv[p][e] * w.z; o[p].w += zqv[p][e] * w.w;
            }
        }
        #pragma unroll
        for (int p = 0; p < 2; ++p)
            *(float4*)(xout + row[p] + c0) = o[p];
    }

    // ---- last block writes the scalars. __syncthreads drains vmcnt(0) for
    // all this block's atomics before tid0 takes a ticket, so ticket
    // gridDim-1 happens-after every marking atomic has completed at L2.
    __syncthreads();
    if (tid == 0) {
        if (atomicAdd(ticket_ctr, 1) == (int)gridDim.x - 1) {
            const float uniq  = (float)atomicAdd(uniq_ctr, 0);
            const float usage = (uniq + ((float)K_CB - uniq) * expf(-1.0f)) / (float)K_CB;
            scal[0] = usage;          // output 3: usage
            scal[1] = uniq;           // output 4: unique (stored as its value)
            scal[2] = 0.0f;           // output 5: percent_masked
        }
    }
}

// ---------------------------------------------------------------------------
extern "C" void kernel_launch(void* const* d_in, const int* in_sizes, int n_in,
                              void* d_out, int out_size, void* d_ws, size_t ws_size,
                              hipStream_t stream) {
    const float* x    = (const float*)d_in[0];   // [16,2048,1024]
    const float* Wenc = (const float*)d_in[1];   // [1024,5]
    const float* Wdec = (const float*)d_in[2];   // [5,1024]

    float* out  = (float*)d_out;
    float* xout = out;                                  // 33554432
    float* ze   = out + 33554432;                       // 163840
    float* zq   = ze + 163840;                          // 163840
    float* scal = zq + 163840;                          // 3 scalars

    int* used = (int*)d_ws;                             // 4375 flags + uniq + ticket

    hipMemsetAsync(used, 0, (K_CB + 2) * sizeof(int), stream);
    fsq_main<<<2048, 256, 0, stream>>>(x, Wenc, Wdec, xout, ze, zq, used, scal);
}

// Round 9
// 44.677 us; speedup vs baseline: 2.0991x; 2.0991x over previous
//
#include <hip/hip_runtime.h>

#define MAX_SEQ   2048
#define LAT_SEQ   1024
#define DIM       1024
#define DLAT      5
#define K_CB      4375
#define ZERO_IDX  2187   // (0+3)*625 + (0+2)*125 + (0+2)*25 + (0+2)*5 + (0+2)

typedef float vf4 __attribute__((ext_vector_type(4)));

__device__ __forceinline__ void nt_store4(float* p, vf4 v) {
    __builtin_nontemporal_store(v, (vf4*)p);
}

// ---------------------------------------------------------------------------
// Fused encode -> quantize -> decode. One wave per 2 (unmasked, masked) token
// pairs, 256-thread blocks, grid 2048. Weights staged in LDS. xout (never
// re-read, 134 MB) uses nontemporal stores so it doesn't evict x from L3;
// ze/zq keep plain stores (4B scattered -> want L2 write merging).
// No fences, no device atomics — scalars are a separate tiny kernel.
__global__ __launch_bounds__(256) void fsq_main(
    const float* __restrict__ x,
    const float* __restrict__ Wenc,   // [1024][5]
    const float* __restrict__ Wdec,   // [5][1024]
    float* __restrict__ xout,         // [32768][1024]
    float* __restrict__ ze,           // [32768][5]
    float* __restrict__ zq,           // [32768][5]
    int*   __restrict__ used)         // [4375], pre-zeroed via memset
{
    __shared__ float wencT[DLAT * DIM];   // [5][1024]
    __shared__ float wdecS[DLAT * DIM];   // [5][1024]

    const int tid  = threadIdx.x;
    const int wave = tid >> 6;
    const int lane = tid & 63;
    const int u0   = (blockIdx.x * 4 + wave) * 2;    // unmasked ordinal base

    int t[2];  long long row[2], rowm[2];
    #pragma unroll
    for (int p = 0; p < 2; ++p) {
        const int u = u0 + p;
        const int b = u >> 10, s = u & 1023;
        t[p]    = b * MAX_SEQ + s;                    // unmasked token
        row[p]  = (long long)t[p] * DIM;
        rowm[p] = row[p] + (long long)LAT_SEQ * DIM;  // masked partner row
    }

    // ---- issue x loads early (8 float4 in flight)
    float4 v[2][4];
    #pragma unroll
    for (int p = 0; p < 2; ++p)
        #pragma unroll
        for (int q = 0; q < 4; ++q)
            v[p][q] = *(const float4*)(x + row[p] + q * 256 + lane * 4);

    // ---- masked partners: independent zero-store work
    const vf4 z4 = {0.f, 0.f, 0.f, 0.f};
    #pragma unroll
    for (int p = 0; p < 2; ++p) {
        #pragma unroll
        for (int q = 0; q < 4; ++q)
            nt_store4(xout + rowm[p] + q * 256 + lane * 4, z4);
        if (lane < DLAT) {
            const int tm = t[p] + LAT_SEQ;
            ze[tm * DLAT + lane] = 0.f;
            zq[tm * DLAT + lane] = 0.f;
        }
    }

    // ---- cooperative weight staging into LDS
    {
        const float4* src = (const float4*)Wdec;      // [5][1024] already coalesced
        float4*       dst = (float4*)wdecS;
        #pragma unroll
        for (int m = 0; m < 5; ++m)
            dst[tid + 256 * m] = src[tid + 256 * m];
        #pragma unroll
        for (int m = 0; m < 20; ++m) {                // WencT[e][d] = Wenc[d][e]
            const int k = tid + 256 * m;
            const int e = k >> 10, d = k & 1023;
            wencT[k] = Wenc[d * DLAT + e];
        }
    }
    __syncthreads();

    // ---- encode: h[p][e] = sum_d x[t_p,d] * Wenc[d,e]
    float acc[2][DLAT] = {};
    #pragma unroll
    for (int q = 0; q < 4; ++q) {
        const int c0 = q * 256 + lane * 4;
        #pragma unroll
        for (int e = 0; e < DLAT; ++e) {
            const float4 w = *(const float4*)(wencT + e * DIM + c0);
            #pragma unroll
            for (int p = 0; p < 2; ++p)
                acc[p][e] += v[p][q].x * w.x + v[p][q].y * w.y
                           + v[p][q].z * w.z + v[p][q].w * w.w;
        }
    }
    #pragma unroll
    for (int p = 0; p < 2; ++p)
        #pragma unroll
        for (int e = 0; e < DLAT; ++e) {
            float a = acc[p][e];
            #pragma unroll
            for (int o = 32; o > 0; o >>= 1) a += __shfl_xor(a, o, 64);
            acc[p][e] = a;
        }

    // ---- quantize: z_q = rint(half * tanh(h))  (rint = half-to-even)
    const float halfv[DLAT] = {3.f, 2.f, 2.f, 2.f, 2.f};
    float zqv[2][DLAT];
    #pragma unroll
    for (int p = 0; p < 2; ++p) {
        int ci[DLAT];
        #pragma unroll
        for (int e = 0; e < DLAT; ++e) {
            const float zsq = halfv[e] * tanhf(acc[p][e]);
            zqv[p][e] = rintf(zsq);
            ci[e]     = (int)zqv[p][e];
        }
        if (lane < DLAT) {
            ze[t[p] * DLAT + lane] = acc[p][lane];
            zq[t[p] * DLAT + lane] = zqv[p][lane];
        }
        if (lane == 0) {
            const int idx = ((((ci[0] + 3) * 5 + (ci[1] + 2)) * 5 + (ci[2] + 2)) * 5
                              + (ci[3] + 2)) * 5 + (ci[4] + 2);
            used[idx] = 1;   // benign race: everyone stores 1
        }
    }

    // ---- decode: x_out[t,d] = sum_e z_q[e] * Wdec[e,d]
    #pragma unroll
    for (int q = 0; q < 4; ++q) {
        const int c0 = q * 256 + lane * 4;
        vf4 o[2] = {{0.f,0.f,0.f,0.f}, {0.f,0.f,0.f,0.f}};
        #pragma unroll
        for (int e = 0; e < DLAT; ++e) {
            const float4 w = *(const float4*)(wdecS + e * DIM + c0);
            #pragma unroll
            for (int p = 0; p < 2; ++p) {
                o[p].x += zqv[p][e] * w.x; o[p].y += zqv[p][e] * w.y;
                o[p].z += zqv[p][e] * w.z; o[p].w += zqv[p][e] * w.w;
            }
        }
        #pragma unroll
        for (int p = 0; p < 2; ++p)
            nt_store4(xout + row[p] + c0, o[p]);
    }
}

// ---------------------------------------------------------------------------
// Reduce usage flags -> unique; zero code is always used (masked tokens) even
// though no wave marks it.
__global__ void finalize(const int* __restrict__ used, float* __restrict__ scal) {
    __shared__ int sh[256];
    const int t = threadIdx.x;
    int sum = 0;
    for (int i = t; i < K_CB; i += 256) sum += used[i];
    sh[t] = sum;
    __syncthreads();
    for (int o = 128; o > 0; o >>= 1) {
        if (t < o) sh[t] += sh[t + o];
        __syncthreads();
    }
    if (t == 0) {
        const float uniq  = (float)sh[0] + (used[ZERO_IDX] ? 0.f : 1.f);
        const float usage = (uniq + ((float)K_CB - uniq) * expf(-1.0f)) / (float)K_CB;
        scal[0] = usage;          // output 3: usage
        scal[1] = uniq;           // output 4: unique (stored as its value)
        scal[2] = 0.0f;           // output 5: percent_masked
    }
}

// ---------------------------------------------------------------------------
extern "C" void kernel_launch(void* const* d_in, const int* in_sizes, int n_in,
                              void* d_out, int out_size, void* d_ws, size_t ws_size,
                              hipStream_t stream) {
    const float* x    = (const float*)d_in[0];   // [16,2048,1024]
    const float* Wenc = (const float*)d_in[1];   // [1024,5]
    const float* Wdec = (const float*)d_in[2];   // [5,1024]

    float* out  = (float*)d_out;
    float* xout = out;                                  // 33554432
    float* ze   = out + 33554432;                       // 163840
    float* zq   = ze + 163840;                          // 163840
    float* scal = zq + 163840;                          // 3 scalars

    int* used = (int*)d_ws;                             // 4375 flags

    hipMemsetAsync(used, 0, K_CB * sizeof(int), stream);
    fsq_main<<<2048, 256, 0, stream>>>(x, Wenc, Wdec, xout, ze, zq, used);
    finalize<<<1, 256, 0, stream>>>(used, scal);
}